// Round 2
// baseline (464.973 us; speedup 1.0000x reference)
//
#include <hip/hip_runtime.h>
#include <hip/hip_bf16.h>

// Problem constants (from reference)
#define BATCH 16384
#define DIM   128
#define HID   1024
#define NK    8
#define OPD   25          // 3*K+1
#define N3    (DIM*OPD)   // 3200

typedef __attribute__((ext_vector_type(8))) short  short8;   // 8 bf16 (4 VGPRs)
typedef __attribute__((ext_vector_type(4))) float  floatx4;  // MFMA C/D frag

// ---------------------------------------------------------------- prep kernels
__global__ void cvt_bf16_kernel(const float* __restrict__ in,
                                __hip_bfloat16* __restrict__ out, int n) {
    int i = blockIdx.x * blockDim.x + threadIdx.x;
    if (i < n) out[i] = __float2bfloat16(in[i]);
}

__global__ void maskmul_bf16_kernel(const float* __restrict__ w,
                                    const float* __restrict__ m,
                                    __hip_bfloat16* __restrict__ out, int n) {
    int i = blockIdx.x * blockDim.x + threadIdx.x;
    if (i < n) out[i] = __float2bfloat16(w[i] * m[i]);
}

// ---------------------------------------------------------------- GEMM
// C[M,N] = A[M,K] * Bw[N,K]^T  (+bias, optional silu->bf16)
// 128x128 tile, BK=64, 256 threads (4 waves, 2x2), each wave 64x64 via 4x4
// mfma_f32_16x16x32_bf16 frags.
// A frag: lane reads A[m = lane&15][k = (lane>>4)*8 + j]
// B frag: lane reads Bw[n = lane&15][k = (lane>>4)*8 + j]
// C/D:    col = lane&15, row = (lane>>4)*4 + reg      [verified m89/m91]
template<int SILU>
__global__ __launch_bounds__(256) void gemm_bt_kernel(
    const unsigned short* __restrict__ A,   // M x K bf16 bits
    const unsigned short* __restrict__ Bw,  // N x K bf16 bits
    const float* __restrict__ bias,         // N
    void* __restrict__ Cout,                // SILU? bf16 : float, M x N
    int M, int N, int Kd)
{
    constexpr int BM = 128, BN = 128, BK = 64;
    constexpr int LS = BK + 8;               // +8 shorts pad = 16B, keeps 16B align
    __shared__ unsigned short As[BM * LS];   // 18,432 B
    __shared__ unsigned short Bs[BN * LS];   // 18,432 B

    const int bn = blockIdx.x * BN;
    const int bm = blockIdx.y * BM;
    const int t    = threadIdx.x;
    const int lane = t & 63;
    const int w    = t >> 6;
    const int wr   = (w >> 1) * 64;   // wave m offset in tile
    const int wc   = (w & 1) * 64;    // wave n offset in tile
    const int lr   = lane & 15;
    const int quad = lane >> 4;

    floatx4 acc[4][4] = {};

    const int r0 = t >> 3;        // 0..31
    const int c0 = (t & 7) * 8;   // 0..56 step 8

    for (int k0 = 0; k0 < Kd; k0 += BK) {
        __syncthreads();
        #pragma unroll
        for (int p = 0; p < 4; p++) {
            const int r = r0 + 32 * p;
            *(uint4*)&As[r * LS + c0] =
                *(const uint4*)&A[(size_t)(bm + r) * Kd + k0 + c0];
            *(uint4*)&Bs[r * LS + c0] =
                *(const uint4*)&Bw[(size_t)(bn + r) * Kd + k0 + c0];
        }
        __syncthreads();
        #pragma unroll
        for (int ks = 0; ks < BK; ks += 32) {
            short8 af[4], bfr[4];
            #pragma unroll
            for (int i = 0; i < 4; i++)
                af[i] = *(const short8*)&As[(wr + i * 16 + lr) * LS + ks + quad * 8];
            #pragma unroll
            for (int j = 0; j < 4; j++)
                bfr[j] = *(const short8*)&Bs[(wc + j * 16 + lr) * LS + ks + quad * 8];
            #pragma unroll
            for (int i = 0; i < 4; i++)
                #pragma unroll
                for (int j = 0; j < 4; j++)
                    acc[i][j] = __builtin_amdgcn_mfma_f32_16x16x32_bf16(
                        af[i], bfr[j], acc[i][j], 0, 0, 0);
        }
    }

    // epilogue
    #pragma unroll
    for (int j = 0; j < 4; j++) {
        const int col = bn + wc + j * 16 + lr;
        const float bv = bias[col];
        #pragma unroll
        for (int i = 0; i < 4; i++) {
            const int rowb = bm + wr + i * 16 + quad * 4;
            #pragma unroll
            for (int r = 0; r < 4; r++) {
                float v = acc[i][j][r] + bv;
                const size_t idx = (size_t)(rowb + r) * N + col;
                if (SILU) {
                    v = v / (1.f + expf(-v));
                    ((__hip_bfloat16*)Cout)[idx] = __float2bfloat16(v);
                } else {
                    ((float*)Cout)[idx] = v;
                }
            }
        }
    }
}

// ---------------------------------------------------------------- spline
// One block per batch row, one thread per dim. All K=8 arrays fully unrolled
// with constant indexing only (stays in VGPRs).
__global__ __launch_bounds__(128) void spline_kernel(
    const float* __restrict__ raw, const float* __restrict__ x,
    float* __restrict__ out, float* __restrict__ lad)
{
    const int b = blockIdx.x;
    const int d = threadIdx.x;
    const float* r = raw + (size_t)b * N3 + d * OPD;

    float uw[NK], uh[NK], ud[NK + 1];
    #pragma unroll
    for (int j = 0; j < NK; j++)     uw[j] = r[j];
    #pragma unroll
    for (int j = 0; j < NK; j++)     uh[j] = r[NK + j];
    #pragma unroll
    for (int j = 0; j < NK + 1; j++) ud[j] = r[2 * NK + j];

    float cw[NK + 1], ch[NK + 1], dd[NK + 1];
    // widths: softmax -> affine -> cumsum -> normalize
    {
        float mx = uw[0];
        #pragma unroll
        for (int j = 1; j < NK; j++) mx = fmaxf(mx, uw[j]);
        float e[NK], s = 0.f;
        #pragma unroll
        for (int j = 0; j < NK; j++) { e[j] = expf(uw[j] - mx); s += e[j]; }
        const float inv = 1.f / s;
        cw[0] = 0.f;
        #pragma unroll
        for (int j = 0; j < NK; j++) cw[j + 1] = cw[j] + (0.001f + 0.992f * e[j] * inv);
        const float icn = 1.f / fmaxf(cw[NK], 1e-12f);
        #pragma unroll
        for (int j = 0; j <= NK; j++) cw[j] *= icn;
    }
    // heights: same
    {
        float mx = uh[0];
        #pragma unroll
        for (int j = 1; j < NK; j++) mx = fmaxf(mx, uh[j]);
        float e[NK], s = 0.f;
        #pragma unroll
        for (int j = 0; j < NK; j++) { e[j] = expf(uh[j] - mx); s += e[j]; }
        const float inv = 1.f / s;
        ch[0] = 0.f;
        #pragma unroll
        for (int j = 0; j < NK; j++) ch[j + 1] = ch[j] + (0.001f + 0.992f * e[j] * inv);
        const float icn = 1.f / fmaxf(ch[NK], 1e-12f);
        #pragma unroll
        for (int j = 0; j <= NK; j++) ch[j] *= icn;
    }
    // derivatives: 0.001 + softplus
    #pragma unroll
    for (int j = 0; j <= NK; j++) {
        const float u = ud[j];
        dd[j] = 0.001f + ((u > 20.f) ? u : log1pf(expf(u)));
    }

    const float xv = x[(size_t)b * DIM + d];
    const bool inside = (xv >= -3.f) && (xv <= 3.f);
    float xs = (xv + 3.f) * (1.f / 6.f);
    xs = fminf(fmaxf(xs, 0.f), 1.f);

    int bid = 0;   // cw[0]=0 <= xs always
    #pragma unroll
    for (int j = 1; j <= NK; j++) if (xs >= cw[j]) bid = j;
    if (bid > NK - 1) bid = NK - 1;

    float xk = 0.f, wk = 0.f, yk = 0.f, hk = 0.f, dk = 0.f, dk1 = 0.f;
    #pragma unroll
    for (int j = 0; j < NK; j++) if (bid == j) {
        xk = cw[j]; wk = cw[j + 1] - cw[j];
        yk = ch[j]; hk = ch[j + 1] - ch[j];
        dk = dd[j]; dk1 = dd[j + 1];
    }

    float t = (xs - xk) / (wk + 1e-12f);
    t = fminf(fmaxf(t, 0.f), 1.f);
    const float a   = (hk + 1e-12f) / (wk + 1e-12f);
    const float omt = 1.f - t;
    const float tt1 = t * omt;
    const float num = a * t * t + dk * tt1;
    const float den = a + (dk + dk1 - 2.f * a) * tt1;
    const float s   = num / (den + 1e-12f);
    const float y   = (yk + hk * s) * 6.f - 3.f;
    const float dnum = a * a * (dk1 * t * t + 2.f * a * tt1 + dk * omt * omt);
    const float dydx = dnum / (den * den + 1e-12f);

    out[(size_t)b * DIM + d] = inside ? y : xv;
    float l = inside ? logf(fmaxf(dydx, 1e-12f)) : 0.f;

    // logdet reduction over 128 threads (2 waves)
    #pragma unroll
    for (int off = 32; off > 0; off >>= 1) l += __shfl_down(l, off, 64);
    __shared__ float ls[2];
    if ((threadIdx.x & 63) == 0) ls[threadIdx.x >> 6] = l;
    __syncthreads();
    if (threadIdx.x == 0) lad[b] = ls[0] + ls[1];
}

// ---------------------------------------------------------------- launch
extern "C" void kernel_launch(void* const* d_in, const int* in_sizes, int n_in,
                              void* d_out, int out_size, void* d_ws, size_t ws_size,
                              hipStream_t stream) {
    const float* x  = (const float*)d_in[0];
    const float* W1 = (const float*)d_in[1];
    const float* b1 = (const float*)d_in[2];
    const float* W2 = (const float*)d_in[3];
    const float* b2 = (const float*)d_in[4];
    const float* W3 = (const float*)d_in[5];
    const float* b3 = (const float*)d_in[6];
    const float* m1 = (const float*)d_in[7];
    const float* m2 = (const float*)d_in[8];
    const float* m3 = (const float*)d_in[9];

    // ---- adaptive batch chunking so the workspace always fits ----
    // static (weights, bf16): w1b 256KB + w2b 2MB + w3b 6.25MB = 8,912,896 B
    // per-chunk C: xb 256C + h1b 2048C + h2b 2048C + raw(fp32) 12800C = 17152C
    constexpr size_t W_BYTES = (size_t)HID * DIM * 2 + (size_t)HID * HID * 2
                             + (size_t)N3 * HID * 2;             // 8,912,896
    int C = BATCH;
    while (C > 512 && W_BYTES + (size_t)17152 * C > ws_size) C >>= 1;
    // C=16384 -> 290MB, 8192 -> 149MB, 4096 -> 79MB, 2048 -> 44MB, 1024 -> 26.5MB

    char* ws = (char*)d_ws;
    const size_t OFF_W1B = 0;
    const size_t OFF_W2B = OFF_W1B + (size_t)HID * DIM * 2;
    const size_t OFF_W3B = OFF_W2B + (size_t)HID * HID * 2;
    const size_t OFF_XB  = OFF_W3B + (size_t)N3 * HID * 2;       // 8,912,896
    const size_t OFF_H1B = OFF_XB  + (size_t)C * DIM * 2;
    const size_t OFF_H2B = OFF_H1B + (size_t)C * HID * 2;
    const size_t OFF_RAW = OFF_H2B + (size_t)C * HID * 2;

    __hip_bfloat16* w1b = (__hip_bfloat16*)(ws + OFF_W1B);
    __hip_bfloat16* w2b = (__hip_bfloat16*)(ws + OFF_W2B);
    __hip_bfloat16* w3b = (__hip_bfloat16*)(ws + OFF_W3B);
    __hip_bfloat16* xb  = (__hip_bfloat16*)(ws + OFF_XB);
    __hip_bfloat16* h1b = (__hip_bfloat16*)(ws + OFF_H1B);
    __hip_bfloat16* h2b = (__hip_bfloat16*)(ws + OFF_H2B);
    float*          raw = (float*)(ws + OFF_RAW);

    // weight prep (once)
    maskmul_bf16_kernel<<<(HID * DIM) / 256, 256, 0, stream>>>(W1, m1, w1b, HID * DIM);
    maskmul_bf16_kernel<<<(HID * HID) / 256, 256, 0, stream>>>(W2, m2, w2b, HID * HID);
    maskmul_bf16_kernel<<<(N3 * HID) / 256, 256, 0, stream>>>(W3, m3, w3b, N3 * HID);

    float* out_p = (float*)d_out;
    float* lad_p = out_p + (size_t)BATCH * DIM;

    for (int cs = 0; cs < BATCH; cs += C) {
        const float* xc = x + (size_t)cs * DIM;
        cvt_bf16_kernel<<<(C * DIM) / 256, 256, 0, stream>>>(xc, xb, C * DIM);
        gemm_bt_kernel<1><<<dim3(HID / 128, C / 128), 256, 0, stream>>>(
            (const unsigned short*)xb, (const unsigned short*)w1b, b1, h1b,
            C, HID, DIM);
        gemm_bt_kernel<1><<<dim3(HID / 128, C / 128), 256, 0, stream>>>(
            (const unsigned short*)h1b, (const unsigned short*)w2b, b2, h2b,
            C, HID, HID);
        gemm_bt_kernel<0><<<dim3(N3 / 128, C / 128), 256, 0, stream>>>(
            (const unsigned short*)h2b, (const unsigned short*)w3b, b3, raw,
            C, N3, HID);
        spline_kernel<<<C, 128, 0, stream>>>(raw, xc,
                                             out_p + (size_t)cs * DIM, lad_p + cs);
    }
}